// Round 9
// baseline (191.806 us; speedup 1.0000x reference)
//
#include <hip/hip_runtime.h>
#include <hip/hip_bf16.h>

typedef unsigned short u16;

// Problem constants
#define BB 4
#define TT 2048
#define DIM 512
#define NH 8
#define DH 64
#define DECAY 0.9f

// Retention chunking
#define CC 64
#define NC 32
#define BHN 32

// Scan chunking: CHS=32
#define CHS 32
#define NSC 64

// GEMM tiling: 128x64 (grid-size > per-block-depth at these small N)
#define TM 128
#define TN 64
#define BK 64

// retention LDS row stride (u16)
#define SS 72

typedef __attribute__((ext_vector_type(8))) short bf16x8;
typedef __attribute__((ext_vector_type(4))) float f32x4;

__device__ __forceinline__ u16 f2bfu(float f) {
  union { float f; unsigned int u; } c; c.f = f;
  unsigned int u = c.u + 0x7FFFu + ((c.u >> 16) & 1u);  // RNE
  return (u16)(u >> 16);
}
__device__ __forceinline__ float bf2f(u16 u) {
  union { unsigned int u; float f; } c; c.u = ((unsigned int)u) << 16;
  return c.f;
}

__device__ __forceinline__ void gl_lds16(const void* g, void* l) {
  __builtin_amdgcn_global_load_lds(
      (const __attribute__((address_space(1))) void*)g,
      (__attribute__((address_space(3))) void*)(unsigned int)(unsigned long long)l,
      16, 0, 0);
}

// ---------------------------------------------------------------------------
// GEMM tile body, TM=128 x TN=64 (m97 staging structure).
// n-tile group (ng*64>>9): 0 -> C0, 1 -> C1, 2 -> C2; per-group sigmoid
// (act_mask), bf16-vs-fp32 store (bf16_mask), optional bf16 Radd addend.
// ---------------------------------------------------------------------------
__device__ __forceinline__ void gemm_tile64(
    int nTile, int mTile, const u16* __restrict__ A, const u16* __restrict__ Bt,
    const float* __restrict__ b0, const float* __restrict__ b1,
    const float* __restrict__ b2,
    void* __restrict__ C0, void* __restrict__ C1, void* __restrict__ C2,
    int act_mask, int bf16_mask, const u16* __restrict__ Radd,
    u16* As, u16* Bs, int tid) {
  int wave = tid >> 6, lane = tid & 63;
  int group = (nTile * TN) >> 9;
  const float* bias = (group == 0) ? b0 : (group == 1) ? b1 : b2;
  void* C = (group == 0) ? C0 : (group == 1) ? C1 : C2;
  int act = (act_mask >> group) & 1;
  int isbf = (bf16_mask >> group) & 1;

  int wm = wave * 32;
  int rowA = lane & 15, khalf = lane >> 4;

  f32x4 acc[2][4];
#pragma unroll
  for (int i = 0; i < 2; ++i)
#pragma unroll
    for (int j = 0; j < 4; ++j) acc[i][j] = (f32x4){0.f, 0.f, 0.f, 0.f};

  const u16* Abase = A + (size_t)mTile * TM * 512;
  const u16* Bbase = Bt + (size_t)nTile * TN * 512;

  for (int kk = 0; kk < 512; kk += BK) {
#pragma unroll
    for (int i = 0; i < 4; ++i) {
      int o = (wave * 4 + i) * 64 + lane;
      int row = o >> 3, gk = (o & 7) ^ (row & 7);
      gl_lds16(Abase + (size_t)row * 512 + kk + gk * 8, &As[o * 8]);
    }
#pragma unroll
    for (int i = 0; i < 2; ++i) {
      int o = (wave * 2 + i) * 64 + lane;
      int row = o >> 3, gk = (o & 7) ^ (row & 7);
      gl_lds16(Bbase + (size_t)row * 512 + kk + gk * 8, &Bs[o * 8]);
    }
    __syncthreads();
#pragma unroll
    for (int k0 = 0; k0 < 2; ++k0) {
      bf16x8 af[2], bfr[4];
#pragma unroll
      for (int mi = 0; mi < 2; ++mi) {
        int rr = wm + mi * 16 + rowA;
        int gk = k0 * 4 + khalf;
        int o = rr * 8 + (gk ^ (rr & 7));
        af[mi] = *(const bf16x8*)&As[o * 8];
      }
#pragma unroll
      for (int ni = 0; ni < 4; ++ni) {
        int rr = ni * 16 + rowA;
        int gk = k0 * 4 + khalf;
        int o = rr * 8 + (gk ^ (rr & 7));
        bfr[ni] = *(const bf16x8*)&Bs[o * 8];
      }
#pragma unroll
      for (int mi = 0; mi < 2; ++mi)
#pragma unroll
        for (int ni = 0; ni < 4; ++ni)
          acc[mi][ni] = __builtin_amdgcn_mfma_f32_16x16x32_bf16(
              af[mi], bfr[ni], acc[mi][ni], 0, 0, 0);
    }
    __syncthreads();
  }
  int cloc = lane & 15, rq = (lane >> 4) * 4;
#pragma unroll
  for (int mi = 0; mi < 2; ++mi) {
#pragma unroll
    for (int r = 0; r < 4; ++r) {
      int m = mTile * TM + wm + mi * 16 + rq + r;
#pragma unroll
      for (int ni = 0; ni < 4; ++ni) {
        int n = (nTile * TN + ni * 16 + cloc) & 511;
        float vv = acc[mi][ni][r] + bias[n];
        if (act) vv = 1.0f / (1.0f + __expf(-vv));
        if (Radd) vv += bf2f(Radd[(size_t)m * 512 + n]);
        if (isbf) ((u16*)C)[(size_t)m * 512 + n] = f2bfu(vv);
        else ((float*)C)[(size_t)m * 512 + n] = vv;
      }
    }
  }
}

// ---------------------------------------------------------------------------
// K1: blocks [0,1024): wtrans; [1024,5120): cvt q -> bf16
// ---------------------------------------------------------------------------
__global__ __launch_bounds__(256) void k1_prep(
    const float* __restrict__ q, u16* __restrict__ qbf,
    const float* __restrict__ W0, const float* __restrict__ W1,
    const float* __restrict__ W2, const float* __restrict__ W3,
    u16* __restrict__ Wt) {
  __shared__ float t[32][33];
  int bx = blockIdx.x, tid = threadIdx.x;
  if (bx < 1024) {
    int m = bx >> 8, rem = bx & 255;
    int n0 = (rem & 15) * 32, k0 = (rem >> 4) * 32;
    const float* W = (m == 0) ? W0 : (m == 1) ? W1 : (m == 2) ? W2 : W3;
    int tx = tid & 31, ty = tid >> 5;
#pragma unroll
    for (int r = 0; r < 32; r += 8)
      t[ty + r][tx] = W[(size_t)(k0 + ty + r) * DIM + n0 + tx];
    __syncthreads();
    u16* o = Wt + (size_t)m * DIM * DIM;
#pragma unroll
    for (int r = 0; r < 32; r += 8)
      o[(size_t)(n0 + ty + r) * DIM + k0 + tx] = f2bfu(t[tx][ty + r]);
  } else {
    int i = (bx - 1024) * 256 + tid;
    float4 f = ((const float4*)q)[i];
    ushort4 u;
    u.x = f2bfu(f.x); u.y = f2bfu(f.y); u.z = f2bfu(f.z); u.w = f2bfu(f.w);
    ((ushort4*)qbf)[i] = u;
  }
}

// ---------------------------------------------------------------------------
// K2: blocks [0,1024): gemm a,b (n-tiles 0..15, TN=64); [1024,2048): ret_kv
// ---------------------------------------------------------------------------
__global__ __launch_bounds__(256) void k2_gemmab_retkv(
    const u16* __restrict__ qbf, const u16* __restrict__ WtAll,
    const float* __restrict__ ba, const float* __restrict__ bb,
    const float* __restrict__ bg,
    u16* __restrict__ Ab16, u16* __restrict__ Bb16, u16* __restrict__ Gb16,
    const float* __restrict__ k, const float* __restrict__ v,
    u16* __restrict__ KVTb, u16* __restrict__ VTg) {
  __shared__ __align__(16) u16 smem[TM * BK + TN * BK];  // 24 KB
  int bx = blockIdx.x, tid = threadIdx.x;
  if (bx < 1024) {
    gemm_tile64(bx & 15, bx >> 4, qbf, WtAll, ba, bb, bg, Ab16, Bb16, Gb16,
                0b101, 0b111, nullptr, smem, smem + TM * BK, tid);
    return;
  }
  // ---- ret_kv ----
  int idx = bx - 1024;
  int bh = idx & 31, c = idx >> 5;
  int b = bh >> 3, h = bh & 7;
  int wave = tid >> 6, lane = tid & 63;
  u16* VT = smem;
  u16* KT = smem + 64 * SS;
  size_t base = ((size_t)(b * TT + c * CC)) * DIM + h * DH;
  int row = tid >> 2, part = tid & 3, e0 = part * 16;
  float w = __powf(DECAY, (float)(63 - row));
  {
    const float4* vs = (const float4*)(v + base + (size_t)row * DIM + e0);
    const float4* ks = (const float4*)(k + base + (size_t)row * DIM + e0);
#pragma unroll
    for (int u4 = 0; u4 < 4; ++u4) {
      float4 fv = vs[u4], fk = ks[u4];
      VT[(e0 + u4 * 4 + 0) * SS + row] = f2bfu(fv.x);
      VT[(e0 + u4 * 4 + 1) * SS + row] = f2bfu(fv.y);
      VT[(e0 + u4 * 4 + 2) * SS + row] = f2bfu(fv.z);
      VT[(e0 + u4 * 4 + 3) * SS + row] = f2bfu(fv.w);
      KT[(e0 + u4 * 4 + 0) * SS + row] = f2bfu(fk.x * w);
      KT[(e0 + u4 * 4 + 1) * SS + row] = f2bfu(fk.y * w);
      KT[(e0 + u4 * 4 + 2) * SS + row] = f2bfu(fk.z * w);
      KT[(e0 + u4 * 4 + 3) * SS + row] = f2bfu(fk.w * w);
    }
  }
  __syncthreads();
  {
    int e = row;
    u16* dst = VTg + ((size_t)bh * 64 + e) * TT + c * 64 + part * 16;
    *(uint4*)dst = *(const uint4*)&VT[e * SS + part * 16];
    *(uint4*)(dst + 8) = *(const uint4*)&VT[e * SS + part * 16 + 8];
  }
  int wm = (wave >> 1) * 32, wn = (wave & 1) * 32;
  int rowA = lane & 15, khalf = lane >> 4;
  f32x4 acc[2][2];
#pragma unroll
  for (int i = 0; i < 2; ++i)
#pragma unroll
    for (int j = 0; j < 2; ++j) acc[i][j] = (f32x4){0.f, 0.f, 0.f, 0.f};
#pragma unroll
  for (int k0 = 0; k0 < 2; ++k0) {
    int gk = k0 * 4 + khalf;
    bf16x8 af[2], bfr[2];
#pragma unroll
    for (int mi = 0; mi < 2; ++mi)
      af[mi] = *(const bf16x8*)&VT[(wm + mi * 16 + rowA) * SS + gk * 8];
#pragma unroll
    for (int ni = 0; ni < 2; ++ni)
      bfr[ni] = *(const bf16x8*)&KT[(wn + ni * 16 + rowA) * SS + gk * 8];
#pragma unroll
    for (int mi = 0; mi < 2; ++mi)
#pragma unroll
      for (int ni = 0; ni < 2; ++ni)
        acc[mi][ni] = __builtin_amdgcn_mfma_f32_16x16x32_bf16(
            af[mi], bfr[ni], acc[mi][ni], 0, 0, 0);
  }
  int cloc = lane & 15, rq = (lane >> 4) * 4;
  u16* o = KVTb + ((size_t)(c * BHN + bh)) * 4096;
#pragma unroll
  for (int mi = 0; mi < 2; ++mi)
#pragma unroll
    for (int r = 0; r < 4; ++r) {
      int e = wm + mi * 16 + rq + r;
#pragma unroll
      for (int ni = 0; ni < 2; ++ni)
        o[e * 64 + (wn + ni * 16 + cloc)] = f2bfu(acc[mi][ni][r]);
    }
}

// ---------------------------------------------------------------------------
// K3: [0,512): gemm g (n-tiles 16..23, TN=64); [512,1024): scan_part;
//     [1024,1536): ret_scan
// ---------------------------------------------------------------------------
__global__ __launch_bounds__(256) void k3_gemmg_part_retscan(
    const u16* __restrict__ qbf, const u16* __restrict__ WtAll,
    const float* __restrict__ ba, const float* __restrict__ bb,
    const float* __restrict__ bg,
    u16* __restrict__ Ab16, u16* __restrict__ Bb16, u16* __restrict__ Gb16,
    float* __restrict__ SA, float* __restrict__ SB,
    const u16* __restrict__ KVTb, u16* __restrict__ Ptb) {
  __shared__ __align__(16) u16 smem[TM * BK + TN * BK];
  int bx = blockIdx.x, tid = threadIdx.x;
  if (bx < 512) {
    gemm_tile64(16 + (bx & 7), bx >> 3, qbf, WtAll, ba, bb, bg,
                Ab16, Bb16, Gb16, 0b101, 0b111, nullptr,
                smem, smem + TM * BK, tid);
  } else if (bx < 1024) {
    int bxx = bx - 512;
    int ci = bxx >> 3, grp = bxx & 7;
    int ch = grp * 256 + tid;
    int bb2 = ch >> 9, d = ch & 511;
    size_t base = ((size_t)bb2 * TT + ci * CHS) * DIM + d;
    float h = 0.f, pA = 1.f;
#pragma unroll
    for (int t = 0; t < CHS; ++t) {
      float av = bf2f(Ab16[base + (size_t)t * DIM]);
      float bv = bf2f(Bb16[base + (size_t)t * DIM]);
      h = fmaf(av, h, bv);
      pA *= av;
    }
    SA[ci * 2048 + ch] = pA;
    SB[ci * 2048 + ch] = h;
  } else {
    int gid = (bx - 1024) * 256 + tid;
    int bh = gid >> 12, ed = gid & 4095;
    float carry = 0.f;
    const float dC = __powf(DECAY, (float)CC);
    for (int c = 0; c < NC; ++c) {
      size_t idx = ((size_t)(c * BHN + bh)) * 4096 + ed;
      Ptb[idx] = f2bfu(carry);
      carry = fmaf(dC, carry, bf2f(KVTb[idx]));
    }
  }
}

// ---------------------------------------------------------------------------
// K4: [0,512): scan_apply with inline carry-lookback; [512,1536): ret_out
// ---------------------------------------------------------------------------
__global__ __launch_bounds__(256) void k4_apply_retout(
    const u16* __restrict__ Ab16, const u16* __restrict__ Bb16,
    const u16* __restrict__ g, const float* __restrict__ SA,
    const float* __restrict__ SB, u16* __restrict__ hg,
    const u16* __restrict__ qbf, const float* __restrict__ kg,
    const u16* __restrict__ VTg, const u16* __restrict__ Ptb,
    u16* __restrict__ routb) {
  __shared__ __align__(16) u16 Sa[64 * SS];
  __shared__ float dp[66];
  int bx = blockIdx.x, tid = threadIdx.x;
  if (bx < 512) {
    int ci = bx >> 3, grp = bx & 7;
    int ch = grp * 256 + tid;
    int bb = ch >> 9, d = ch & 511;
    float carry = 0.f;
    for (int p = 0; p < ci; ++p)
      carry = fmaf(SA[p * 2048 + ch], carry, SB[p * 2048 + ch]);
    size_t base = ((size_t)bb * TT + ci * CHS) * DIM + d;
    float h = carry;
#pragma unroll
    for (int t = 0; t < CHS; ++t) {
      size_t idx = base + (size_t)t * DIM;
      h = fmaf(bf2f(Ab16[idx]), h, bf2f(Bb16[idx]));
      hg[idx] = f2bfu(h * bf2f(g[idx]));
    }
    return;
  }
  // ---- ret_out ----
  int idx2 = bx - 512;
  int bh = idx2 & 31, c = idx2 >> 5;
  int b = bh >> 3, h = bh & 7;
  int wave = tid >> 6, lane = tid & 63;
  size_t base = ((size_t)(b * TT + c * CC)) * DIM + h * DH;
  if (tid < 66) dp[tid] = __powf(DECAY, (float)tid);

  int wm = (wave >> 1) * 32, wn = (wave & 1) * 32;
  int rowA = lane & 15, khalf = lane >> 4;

  bf16x8 afq[2][2];
#pragma unroll
  for (int k0 = 0; k0 < 2; ++k0)
#pragma unroll
    for (int mi = 0; mi < 2; ++mi)
      afq[k0][mi] = *(const bf16x8*)(qbf + base +
          (size_t)(wm + mi * 16 + rowA) * 512 + (k0 * 4 + khalf) * 8);
  bf16x8 bfk[2][2];
#pragma unroll
  for (int k0 = 0; k0 < 2; ++k0)
#pragma unroll
    for (int ni = 0; ni < 2; ++ni) {
      const float* kp = kg + base + (size_t)(wn + ni * 16 + rowA) * 512 +
                        (k0 * 4 + khalf) * 8;
      float4 f0 = *(const float4*)kp;
      float4 f1 = *(const float4*)(kp + 4);
      bf16x8 t;
      t[0] = (short)f2bfu(f0.x); t[1] = (short)f2bfu(f0.y);
      t[2] = (short)f2bfu(f0.z); t[3] = (short)f2bfu(f0.w);
      t[4] = (short)f2bfu(f1.x); t[5] = (short)f2bfu(f1.y);
      t[6] = (short)f2bfu(f1.z); t[7] = (short)f2bfu(f1.w);
      bfk[k0][ni] = t;
    }

  f32x4 accS[2][2];
#pragma unroll
  for (int i = 0; i < 2; ++i)
#pragma unroll
    for (int j = 0; j < 2; ++j) accS[i][j] = (f32x4){0.f, 0.f, 0.f, 0.f};
#pragma unroll
  for (int k0 = 0; k0 < 2; ++k0)
#pragma unroll
    for (int mi = 0; mi < 2; ++mi)
#pragma unroll
      for (int ni = 0; ni < 2; ++ni)
        accS[mi][ni] = __builtin_amdgcn_mfma_f32_16x16x32_bf16(
            afq[k0][mi], bfk[k0][ni], accS[mi][ni], 0, 0, 0);
  __syncthreads();  // dp ready

  int cloc = lane & 15, rq = (lane >> 4) * 4;
#pragma unroll
  for (int mi = 0; mi < 2; ++mi)
#pragma unroll
    for (int ni = 0; ni < 2; ++ni)
#pragma unroll
      for (int r = 0; r < 4; ++r) {
        int i = wm + mi * 16 + rq + r;
        int j = wn + ni * 16 + cloc;
        float sv = (j <= i) ? accS[mi][ni][r] * dp[i - j] : 0.f;
        Sa[i * SS + j] = f2bfu(sv);
      }
#pragma unroll
  for (int mi = 0; mi < 2; ++mi) {
    float s = dp[wm + mi * 16 + rowA + 1];
#pragma unroll
    for (int k0 = 0; k0 < 2; ++k0) {
      bf16x8 t = afq[k0][mi];
#pragma unroll
      for (int u = 0; u < 8; ++u)
        t[u] = (short)f2bfu(bf2f((u16)t[u]) * s);
      afq[k0][mi] = t;
    }
  }
  __syncthreads();  // Sa ready

  f32x4 accO[2][2];
#pragma unroll
  for (int i = 0; i < 2; ++i)
#pragma unroll
    for (int j = 0; j < 2; ++j) accO[i][j] = (f32x4){0.f, 0.f, 0.f, 0.f};
#pragma unroll
  for (int k0 = 0; k0 < 4; ++k0) {
    bf16x8 af[2], bfv[2];
#pragma unroll
    for (int mi = 0; mi < 2; ++mi) {
      if (k0 < 2)
        af[mi] = *(const bf16x8*)&Sa[(wm + mi * 16 + rowA) * SS +
                                     (k0 * 4 + khalf) * 8];
      else
        af[mi] = afq[k0 - 2][mi];
    }
#pragma unroll
    for (int ni = 0; ni < 2; ++ni) {
      int e = wn + ni * 16 + rowA;
      if (k0 < 2)
        bfv[ni] = *(const bf16x8*)(VTg + ((size_t)bh * 64 + e) * TT + c * 64 +
                                   (k0 * 4 + khalf) * 8);
      else
        bfv[ni] = *(const bf16x8*)(Ptb + ((size_t)(c * BHN + bh)) * 4096 +
                                   e * 64 + ((k0 - 2) * 4 + khalf) * 8);
    }
#pragma unroll
    for (int mi = 0; mi < 2; ++mi)
#pragma unroll
      for (int ni = 0; ni < 2; ++ni)
        accO[mi][ni] = __builtin_amdgcn_mfma_f32_16x16x32_bf16(
            af[mi], bfv[ni], accO[mi][ni], 0, 0, 0);
  }
#pragma unroll
  for (int mi = 0; mi < 2; ++mi)
#pragma unroll
    for (int r = 0; r < 4; ++r) {
      int i = wm + mi * 16 + rq + r;
#pragma unroll
      for (int ni = 0; ni < 2; ++ni) {
        int e = wn + ni * 16 + cloc;
        routb[base + (size_t)i * 512 + e] = f2bfu(accO[mi][ni][r]);
      }
    }
}

// ---------------------------------------------------------------------------
// K5: gemm2 (512 blocks, TN=64): out = (h*g) @ Wo + bo + r_out
// ---------------------------------------------------------------------------
__global__ __launch_bounds__(256) void k5_gemm2(
    const u16* __restrict__ hgbf, const u16* __restrict__ Wto,
    const float* __restrict__ bo, float* __restrict__ out,
    const u16* __restrict__ routb) {
  __shared__ __align__(16) u16 smem[TM * BK + TN * BK];
  gemm_tile64(blockIdx.x & 7, blockIdx.x >> 3, hgbf, Wto, bo, bo, bo,
              out, out, out, 0, 0, routb, smem, smem + TM * BK, threadIdx.x);
}

// ---------------------------------------------------------------------------
extern "C" void kernel_launch(void* const* d_in, const int* in_sizes, int n_in,
                              void* d_out, int out_size, void* d_ws, size_t ws_size,
                              hipStream_t stream) {
  const float* q  = (const float*)d_in[0];
  const float* k  = (const float*)d_in[1];
  const float* v  = (const float*)d_in[2];
  const float* Wa = (const float*)d_in[3];
  const float* ba = (const float*)d_in[4];
  const float* Wb = (const float*)d_in[5];
  const float* bb = (const float*)d_in[6];
  const float* Wg = (const float*)d_in[7];
  const float* bg = (const float*)d_in[8];
  const float* Wo = (const float*)d_in[9];
  const float* bo = (const float*)d_in[10];
  float* out = (float*)d_out;
  float* ws = (float*)d_ws;

  const size_t NEL = (size_t)BB * TT * DIM;  // 4,194,304
  float* SA = ws;
  float* SB = SA + NSC * 2048;
  u16* up = (u16*)(SB + NSC * 2048);
  u16* Ab16  = up;  up += NEL;               // a bf16
  u16* Bb16  = up;  up += NEL;               // b bf16
  u16* Gb16  = up;  up += NEL;               // g bf16
  u16* qbf   = up;  up += NEL;               // q bf16
  u16* hgbf  = up;  up += NEL;               // h*g bf16
  u16* WtAll = up;  up += 4 * DIM * DIM;     // W^T bf16
  u16* KVTb  = up;  up += (size_t)NC * BHN * 4096;
  u16* Ptb   = up;  up += (size_t)NC * BHN * 4096;
  u16* VTg   = up;  up += (size_t)BHN * 64 * TT;
  u16* routb = up;  up += NEL;               // r_out bf16

  k1_prep<<<5120, 256, 0, stream>>>(q, qbf, Wa, Wb, Wg, Wo, WtAll);

  k2_gemmab_retkv<<<2048, 256, 0, stream>>>(qbf, WtAll, ba, bb, bg,
                                            Ab16, Bb16, Gb16, k, v, KVTb, VTg);

  k3_gemmg_part_retscan<<<1536, 256, 0, stream>>>(qbf, WtAll, ba, bb, bg,
                                                  Ab16, Bb16, Gb16,
                                                  SA, SB, KVTb, Ptb);

  k4_apply_retout<<<1536, 256, 0, stream>>>(Ab16, Bb16, Gb16, SA, SB, hgbf,
                                            qbf, k, VTg, Ptb, routb);

  k5_gemm2<<<512, 256, 0, stream>>>(hgbf, WtAll + 3 * DIM * DIM,
                                    bo, out, routb);
}

// Round 10
// 174.638 us; speedup vs baseline: 1.0983x; 1.0983x over previous
//
#include <hip/hip_runtime.h>
#include <hip/hip_bf16.h>

typedef unsigned short u16;

// Problem constants
#define BB 4
#define TT 2048
#define DIM 512
#define NH 8
#define DH 64
#define DECAY 0.9f

// Retention chunking
#define CC 64
#define NC 32
#define BHN 32

// Scan chunking: CHS=32
#define CHS 32
#define NSC 64

// GEMM tiling: 128x128 for gemm1 (12 n-tiles, 768 blocks = 3/CU in K2);
// 128x64 for gemm2 (N=512 -> 512 blocks = 2/CU). R9 showed TN=64 for gemm1
// regresses (A-refetch doubles with 24 n-tiles).
#define TM 128
#define TN 128
#define BK 64

// retention LDS row stride (u16)
#define SS 72

typedef __attribute__((ext_vector_type(8))) short bf16x8;
typedef __attribute__((ext_vector_type(4))) float f32x4;

__device__ __forceinline__ u16 f2bfu(float f) {
  union { float f; unsigned int u; } c; c.f = f;
  unsigned int u = c.u + 0x7FFFu + ((c.u >> 16) & 1u);  // RNE
  return (u16)(u >> 16);
}
__device__ __forceinline__ float bf2f(u16 u) {
  union { unsigned int u; float f; } c; c.u = ((unsigned int)u) << 16;
  return c.f;
}

__device__ __forceinline__ void gl_lds16(const void* g, void* l) {
  __builtin_amdgcn_global_load_lds(
      (const __attribute__((address_space(1))) void*)g,
      (__attribute__((address_space(3))) void*)(unsigned int)(unsigned long long)l,
      16, 0, 0);
}

// ---------------------------------------------------------------------------
// GEMM tile body, TM=128 x TN=128 (m97 structure), bf16 outputs.
// group (nTile*TN >> 9): 0 -> C0, 1 -> C1, 2 -> C2; sigmoid per act_mask.
// ---------------------------------------------------------------------------
__device__ __forceinline__ void gemm_tile(
    int nTile, int mTile, const u16* __restrict__ A, const u16* __restrict__ Bt,
    const float* __restrict__ b0, const float* __restrict__ b1,
    const float* __restrict__ b2,
    u16* __restrict__ C0, u16* __restrict__ C1, u16* __restrict__ C2,
    int act_mask, u16* As, u16* Bs, int tid) {
  int wave = tid >> 6, lane = tid & 63;
  int group = (nTile * TN) >> 9;
  const float* bias = (group == 0) ? b0 : (group == 1) ? b1 : b2;
  u16* C = (group == 0) ? C0 : (group == 1) ? C1 : C2;
  int act = (act_mask >> group) & 1;

  int wm = (wave >> 1) * 64, wn = (wave & 1) * 64;
  int rowA = lane & 15, khalf = lane >> 4;

  f32x4 acc[4][4];
#pragma unroll
  for (int i = 0; i < 4; ++i)
#pragma unroll
    for (int j = 0; j < 4; ++j) acc[i][j] = (f32x4){0.f, 0.f, 0.f, 0.f};

  const u16* Abase = A + (size_t)mTile * TM * 512;
  const u16* Bbase = Bt + (size_t)nTile * TN * 512;

  for (int kk = 0; kk < 512; kk += BK) {
#pragma unroll
    for (int i = 0; i < 4; ++i) {
      int o = (wave * 4 + i) * 64 + lane;
      int row = o >> 3, gk = (o & 7) ^ (row & 7);
      gl_lds16(Abase + (size_t)row * 512 + kk + gk * 8, &As[o * 8]);
    }
#pragma unroll
    for (int i = 0; i < 4; ++i) {
      int o = (wave * 4 + i) * 64 + lane;
      int row = o >> 3, gk = (o & 7) ^ (row & 7);
      gl_lds16(Bbase + (size_t)row * 512 + kk + gk * 8, &Bs[o * 8]);
    }
    __syncthreads();
#pragma unroll
    for (int k0 = 0; k0 < 2; ++k0) {
      bf16x8 af[4], bfr[4];
#pragma unroll
      for (int mi = 0; mi < 4; ++mi) {
        int rr = wm + mi * 16 + rowA;
        int gk = k0 * 4 + khalf;
        int o = rr * 8 + (gk ^ (rr & 7));
        af[mi] = *(const bf16x8*)&As[o * 8];
      }
#pragma unroll
      for (int ni = 0; ni < 4; ++ni) {
        int rr = wn + ni * 16 + rowA;
        int gk = k0 * 4 + khalf;
        int o = rr * 8 + (gk ^ (rr & 7));
        bfr[ni] = *(const bf16x8*)&Bs[o * 8];
      }
#pragma unroll
      for (int mi = 0; mi < 4; ++mi)
#pragma unroll
        for (int ni = 0; ni < 4; ++ni)
          acc[mi][ni] = __builtin_amdgcn_mfma_f32_16x16x32_bf16(
              af[mi], bfr[ni], acc[mi][ni], 0, 0, 0);
    }
    __syncthreads();
  }
  int cloc = lane & 15, rq = (lane >> 4) * 4;
#pragma unroll
  for (int mi = 0; mi < 4; ++mi) {
#pragma unroll
    for (int r = 0; r < 4; ++r) {
      int m = mTile * TM + wm + mi * 16 + rq + r;
#pragma unroll
      for (int ni = 0; ni < 4; ++ni) {
        int n = (nTile * TN + wn + ni * 16 + cloc) & 511;
        float vv = acc[mi][ni][r] + bias[n];
        if (act) vv = 1.0f / (1.0f + __expf(-vv));
        C[(size_t)m * 512 + n] = f2bfu(vv);
      }
    }
  }
}

// ---------------------------------------------------------------------------
// GEMM tile body, TM=128 x TN=64 (gemm2): fp32 out = A@Bt^T + bias + Radd
// ---------------------------------------------------------------------------
__device__ __forceinline__ void gemm_tile64(
    int nTile, int mTile, const u16* __restrict__ A, const u16* __restrict__ Bt,
    const float* __restrict__ bias, float* __restrict__ C,
    const u16* __restrict__ Radd, u16* As, u16* Bs, int tid) {
  int wave = tid >> 6, lane = tid & 63;
  int wm = wave * 32;
  int rowA = lane & 15, khalf = lane >> 4;

  f32x4 acc[2][4];
#pragma unroll
  for (int i = 0; i < 2; ++i)
#pragma unroll
    for (int j = 0; j < 4; ++j) acc[i][j] = (f32x4){0.f, 0.f, 0.f, 0.f};

  const u16* Abase = A + (size_t)mTile * TM * 512;
  const u16* Bbase = Bt + (size_t)nTile * 64 * 512;

  for (int kk = 0; kk < 512; kk += BK) {
#pragma unroll
    for (int i = 0; i < 4; ++i) {
      int o = (wave * 4 + i) * 64 + lane;
      int row = o >> 3, gk = (o & 7) ^ (row & 7);
      gl_lds16(Abase + (size_t)row * 512 + kk + gk * 8, &As[o * 8]);
    }
#pragma unroll
    for (int i = 0; i < 2; ++i) {
      int o = (wave * 2 + i) * 64 + lane;
      int row = o >> 3, gk = (o & 7) ^ (row & 7);
      gl_lds16(Bbase + (size_t)row * 512 + kk + gk * 8, &Bs[o * 8]);
    }
    __syncthreads();
#pragma unroll
    for (int k0 = 0; k0 < 2; ++k0) {
      bf16x8 af[2], bfr[4];
#pragma unroll
      for (int mi = 0; mi < 2; ++mi) {
        int rr = wm + mi * 16 + rowA;
        int gk = k0 * 4 + khalf;
        int o = rr * 8 + (gk ^ (rr & 7));
        af[mi] = *(const bf16x8*)&As[o * 8];
      }
#pragma unroll
      for (int ni = 0; ni < 4; ++ni) {
        int rr = ni * 16 + rowA;
        int gk = k0 * 4 + khalf;
        int o = rr * 8 + (gk ^ (rr & 7));
        bfr[ni] = *(const bf16x8*)&Bs[o * 8];
      }
#pragma unroll
      for (int mi = 0; mi < 2; ++mi)
#pragma unroll
        for (int ni = 0; ni < 4; ++ni)
          acc[mi][ni] = __builtin_amdgcn_mfma_f32_16x16x32_bf16(
              af[mi], bfr[ni], acc[mi][ni], 0, 0, 0);
    }
    __syncthreads();
  }
  int cloc = lane & 15, rq = (lane >> 4) * 4;
#pragma unroll
  for (int mi = 0; mi < 2; ++mi) {
#pragma unroll
    for (int r = 0; r < 4; ++r) {
      int m = mTile * TM + wm + mi * 16 + rq + r;
#pragma unroll
      for (int ni = 0; ni < 4; ++ni) {
        int n = nTile * 64 + ni * 16 + cloc;
        float vv = acc[mi][ni][r] + bias[n] + bf2f(Radd[(size_t)m * 512 + n]);
        C[(size_t)m * 512 + n] = vv;
      }
    }
  }
}

// ---------------------------------------------------------------------------
// K1: [0,1024): ret_kv (deepest, scheduled first); [1024,2048): wtrans;
//     [2048,6144): cvt q -> bf16.  ret_kv depends only on k,v.
// ---------------------------------------------------------------------------
__global__ __launch_bounds__(256) void k1_prep_retkv(
    const float* __restrict__ q, u16* __restrict__ qbf,
    const float* __restrict__ W0, const float* __restrict__ W1,
    const float* __restrict__ W2, const float* __restrict__ W3,
    u16* __restrict__ Wt,
    const float* __restrict__ k, const float* __restrict__ v,
    u16* __restrict__ KVTb, u16* __restrict__ VTg) {
  __shared__ __align__(16) u16 smem[2 * 64 * SS];  // retkv VT+KT (18.4 KB)
  __shared__ float t[32][33];                      // wtrans (4.2 KB)
  int bx = blockIdx.x, tid = threadIdx.x;
  if (bx < 1024) {
    // ---- ret_kv ----
    int bh = bx & 31, c = bx >> 5;
    int b = bh >> 3, h = bh & 7;
    int wave = tid >> 6, lane = tid & 63;
    u16* VT = smem;
    u16* KT = smem + 64 * SS;
    size_t base = ((size_t)(b * TT + c * CC)) * DIM + h * DH;
    int row = tid >> 2, part = tid & 3, e0 = part * 16;
    float w = __powf(DECAY, (float)(63 - row));
    {
      const float4* vs = (const float4*)(v + base + (size_t)row * DIM + e0);
      const float4* ks = (const float4*)(k + base + (size_t)row * DIM + e0);
#pragma unroll
      for (int u4 = 0; u4 < 4; ++u4) {
        float4 fv = vs[u4], fk = ks[u4];
        VT[(e0 + u4 * 4 + 0) * SS + row] = f2bfu(fv.x);
        VT[(e0 + u4 * 4 + 1) * SS + row] = f2bfu(fv.y);
        VT[(e0 + u4 * 4 + 2) * SS + row] = f2bfu(fv.z);
        VT[(e0 + u4 * 4 + 3) * SS + row] = f2bfu(fv.w);
        KT[(e0 + u4 * 4 + 0) * SS + row] = f2bfu(fk.x * w);
        KT[(e0 + u4 * 4 + 1) * SS + row] = f2bfu(fk.y * w);
        KT[(e0 + u4 * 4 + 2) * SS + row] = f2bfu(fk.z * w);
        KT[(e0 + u4 * 4 + 3) * SS + row] = f2bfu(fk.w * w);
      }
    }
    __syncthreads();
    {
      int e = row;
      u16* dst = VTg + ((size_t)bh * 64 + e) * TT + c * 64 + part * 16;
      *(uint4*)dst = *(const uint4*)&VT[e * SS + part * 16];
      *(uint4*)(dst + 8) = *(const uint4*)&VT[e * SS + part * 16 + 8];
    }
    int wm = (wave >> 1) * 32, wn = (wave & 1) * 32;
    int rowA = lane & 15, khalf = lane >> 4;
    f32x4 acc[2][2];
#pragma unroll
    for (int i = 0; i < 2; ++i)
#pragma unroll
      for (int j = 0; j < 2; ++j) acc[i][j] = (f32x4){0.f, 0.f, 0.f, 0.f};
#pragma unroll
    for (int k0 = 0; k0 < 2; ++k0) {
      int gk = k0 * 4 + khalf;
      bf16x8 af[2], bfr[2];
#pragma unroll
      for (int mi = 0; mi < 2; ++mi)
        af[mi] = *(const bf16x8*)&VT[(wm + mi * 16 + rowA) * SS + gk * 8];
#pragma unroll
      for (int ni = 0; ni < 2; ++ni)
        bfr[ni] = *(const bf16x8*)&KT[(wn + ni * 16 + rowA) * SS + gk * 8];
#pragma unroll
      for (int mi = 0; mi < 2; ++mi)
#pragma unroll
        for (int ni = 0; ni < 2; ++ni)
          acc[mi][ni] = __builtin_amdgcn_mfma_f32_16x16x32_bf16(
              af[mi], bfr[ni], acc[mi][ni], 0, 0, 0);
    }
    int cloc = lane & 15, rq = (lane >> 4) * 4;
    u16* o = KVTb + ((size_t)(c * BHN + bh)) * 4096;
#pragma unroll
    for (int mi = 0; mi < 2; ++mi)
#pragma unroll
      for (int r = 0; r < 4; ++r) {
        int e = wm + mi * 16 + rq + r;
#pragma unroll
        for (int ni = 0; ni < 2; ++ni)
          o[e * 64 + (wn + ni * 16 + cloc)] = f2bfu(acc[mi][ni][r]);
      }
  } else if (bx < 2048) {
    // ---- wtrans ----
    int bx2 = bx - 1024;
    int m = bx2 >> 8, rem = bx2 & 255;
    int n0 = (rem & 15) * 32, k0 = (rem >> 4) * 32;
    const float* W = (m == 0) ? W0 : (m == 1) ? W1 : (m == 2) ? W2 : W3;
    int tx = tid & 31, ty = tid >> 5;
#pragma unroll
    for (int r = 0; r < 32; r += 8)
      t[ty + r][tx] = W[(size_t)(k0 + ty + r) * DIM + n0 + tx];
    __syncthreads();
    u16* o = Wt + (size_t)m * DIM * DIM;
#pragma unroll
    for (int r = 0; r < 32; r += 8)
      o[(size_t)(n0 + ty + r) * DIM + k0 + tx] = f2bfu(t[tx][ty + r]);
  } else {
    // ---- cvt q ----
    int i = (bx - 2048) * 256 + tid;
    float4 f = ((const float4*)q)[i];
    ushort4 u;
    u.x = f2bfu(f.x); u.y = f2bfu(f.y); u.z = f2bfu(f.z); u.w = f2bfu(f.w);
    ((ushort4*)qbf)[i] = u;
  }
}

// ---------------------------------------------------------------------------
// K2: [0,768): full gemm1 (12 n-tiles x 64 m-tiles, TN=128, 3 blocks/CU);
//     [768,1280): ret_scan
// ---------------------------------------------------------------------------
__global__ __launch_bounds__(256) void k2_gemm1_retscan(
    const u16* __restrict__ qbf, const u16* __restrict__ WtAll,
    const float* __restrict__ ba, const float* __restrict__ bb,
    const float* __restrict__ bg,
    u16* __restrict__ Ab16, u16* __restrict__ Bb16, u16* __restrict__ Gb16,
    const u16* __restrict__ KVTb, u16* __restrict__ Ptb) {
  __shared__ __align__(16) u16 smem[TM * BK + TN * BK];  // 32 KB
  int bx = blockIdx.x, tid = threadIdx.x;
  if (bx < 768) {
    gemm_tile(bx % 12, bx / 12, qbf, WtAll, ba, bb, bg, Ab16, Bb16, Gb16,
              0b101, smem, smem + TM * BK, tid);
  } else {
    int gid = (bx - 768) * 256 + tid;
    int bh = gid >> 12, ed = gid & 4095;
    float carry = 0.f;
    const float dC = __powf(DECAY, (float)CC);
    for (int c = 0; c < NC; ++c) {
      size_t idx = ((size_t)(c * BHN + bh)) * 4096 + ed;
      Ptb[idx] = f2bfu(carry);
      carry = fmaf(dC, carry, bf2f(KVTb[idx]));
    }
  }
}

// ---------------------------------------------------------------------------
// K3: scan_part (512 blocks)
// ---------------------------------------------------------------------------
__global__ void k3_part(const u16* __restrict__ Ab16, const u16* __restrict__ Bb16,
                        float* __restrict__ SA, float* __restrict__ SB) {
  int ci = blockIdx.x >> 3, grp = blockIdx.x & 7;
  int ch = grp * 256 + threadIdx.x;
  int bb2 = ch >> 9, d = ch & 511;
  size_t base = ((size_t)bb2 * TT + ci * CHS) * DIM + d;
  float h = 0.f, pA = 1.f;
#pragma unroll
  for (int t = 0; t < CHS; ++t) {
    float av = bf2f(Ab16[base + (size_t)t * DIM]);
    float bv = bf2f(Bb16[base + (size_t)t * DIM]);
    h = fmaf(av, h, bv);
    pA *= av;
  }
  SA[ci * 2048 + ch] = pA;
  SB[ci * 2048 + ch] = h;
}

// ---------------------------------------------------------------------------
// K4: [0,512): scan_apply with inline carry-lookback; [512,1536): ret_out
// ---------------------------------------------------------------------------
__global__ __launch_bounds__(256) void k4_apply_retout(
    const u16* __restrict__ Ab16, const u16* __restrict__ Bb16,
    const u16* __restrict__ g, const float* __restrict__ SA,
    const float* __restrict__ SB, u16* __restrict__ hg,
    const u16* __restrict__ qbf, const float* __restrict__ kg,
    const u16* __restrict__ VTg, const u16* __restrict__ Ptb,
    u16* __restrict__ routb) {
  __shared__ __align__(16) u16 Sa[64 * SS];
  __shared__ float dp[66];
  int bx = blockIdx.x, tid = threadIdx.x;
  if (bx < 512) {
    int ci = bx >> 3, grp = bx & 7;
    int ch = grp * 256 + tid;
    int bb = ch >> 9, d = ch & 511;
    float carry = 0.f;
    for (int p = 0; p < ci; ++p)
      carry = fmaf(SA[p * 2048 + ch], carry, SB[p * 2048 + ch]);
    size_t base = ((size_t)bb * TT + ci * CHS) * DIM + d;
    float h = carry;
#pragma unroll
    for (int t = 0; t < CHS; ++t) {
      size_t idx = base + (size_t)t * DIM;
      h = fmaf(bf2f(Ab16[idx]), h, bf2f(Bb16[idx]));
      hg[idx] = f2bfu(h * bf2f(g[idx]));
    }
    return;
  }
  // ---- ret_out ----
  int idx2 = bx - 512;
  int bh = idx2 & 31, c = idx2 >> 5;
  int b = bh >> 3, h = bh & 7;
  int wave = tid >> 6, lane = tid & 63;
  size_t base = ((size_t)(b * TT + c * CC)) * DIM + h * DH;
  if (tid < 66) dp[tid] = __powf(DECAY, (float)tid);

  int wm = (wave >> 1) * 32, wn = (wave & 1) * 32;
  int rowA = lane & 15, khalf = lane >> 4;

  bf16x8 afq[2][2];
#pragma unroll
  for (int k0 = 0; k0 < 2; ++k0)
#pragma unroll
    for (int mi = 0; mi < 2; ++mi)
      afq[k0][mi] = *(const bf16x8*)(qbf + base +
          (size_t)(wm + mi * 16 + rowA) * 512 + (k0 * 4 + khalf) * 8);
  bf16x8 bfk[2][2];
#pragma unroll
  for (int k0 = 0; k0 < 2; ++k0)
#pragma unroll
    for (int ni = 0; ni < 2; ++ni) {
      const float* kp = kg + base + (size_t)(wn + ni * 16 + rowA) * 512 +
                        (k0 * 4 + khalf) * 8;
      float4 f0 = *(const float4*)kp;
      float4 f1 = *(const float4*)(kp + 4);
      bf16x8 t;
      t[0] = (short)f2bfu(f0.x); t[1] = (short)f2bfu(f0.y);
      t[2] = (short)f2bfu(f0.z); t[3] = (short)f2bfu(f0.w);
      t[4] = (short)f2bfu(f1.x); t[5] = (short)f2bfu(f1.y);
      t[6] = (short)f2bfu(f1.z); t[7] = (short)f2bfu(f1.w);
      bfk[k0][ni] = t;
    }

  f32x4 accS[2][2];
#pragma unroll
  for (int i = 0; i < 2; ++i)
#pragma unroll
    for (int j = 0; j < 2; ++j) accS[i][j] = (f32x4){0.f, 0.f, 0.f, 0.f};
#pragma unroll
  for (int k0 = 0; k0 < 2; ++k0)
#pragma unroll
    for (int mi = 0; mi < 2; ++mi)
#pragma unroll
      for (int ni = 0; ni < 2; ++ni)
        accS[mi][ni] = __builtin_amdgcn_mfma_f32_16x16x32_bf16(
            afq[k0][mi], bfk[k0][ni], accS[mi][ni], 0, 0, 0);
  __syncthreads();  // dp ready

  int cloc = lane & 15, rq = (lane >> 4) * 4;
#pragma unroll
  for (int mi = 0; mi < 2; ++mi)
#pragma unroll
    for (int ni = 0; ni < 2; ++ni)
#pragma unroll
      for (int r = 0; r < 4; ++r) {
        int i = wm + mi * 16 + rq + r;
        int j = wn + ni * 16 + cloc;
        float sv = (j <= i) ? accS[mi][ni][r] * dp[i - j] : 0.f;
        Sa[i * SS + j] = f2bfu(sv);
      }
#pragma unroll
  for (int mi = 0; mi < 2; ++mi) {
    float s = dp[wm + mi * 16 + rowA + 1];
#pragma unroll
    for (int k0 = 0; k0 < 2; ++k0) {
      bf16x8 t = afq[k0][mi];
#pragma unroll
      for (int u = 0; u < 8; ++u)
        t[u] = (short)f2bfu(bf2f((u16)t[u]) * s);
      afq[k0][mi] = t;
    }
  }
  __syncthreads();  // Sa ready

  f32x4 accO[2][2];
#pragma unroll
  for (int i = 0; i < 2; ++i)
#pragma unroll
    for (int j = 0; j < 2; ++j) accO[i][j] = (f32x4){0.f, 0.f, 0.f, 0.f};
#pragma unroll
  for (int k0 = 0; k0 < 4; ++k0) {
    bf16x8 af[2], bfv[2];
#pragma unroll
    for (int mi = 0; mi < 2; ++mi) {
      if (k0 < 2)
        af[mi] = *(const bf16x8*)&Sa[(wm + mi * 16 + rowA) * SS +
                                     (k0 * 4 + khalf) * 8];
      else
        af[mi] = afq[k0 - 2][mi];
    }
#pragma unroll
    for (int ni = 0; ni < 2; ++ni) {
      int e = wn + ni * 16 + rowA;
      if (k0 < 2)
        bfv[ni] = *(const bf16x8*)(VTg + ((size_t)bh * 64 + e) * TT + c * 64 +
                                   (k0 * 4 + khalf) * 8);
      else
        bfv[ni] = *(const bf16x8*)(Ptb + ((size_t)(c * BHN + bh)) * 4096 +
                                   e * 64 + ((k0 - 2) * 4 + khalf) * 8);
    }
#pragma unroll
    for (int mi = 0; mi < 2; ++mi)
#pragma unroll
      for (int ni = 0; ni < 2; ++ni)
        accO[mi][ni] = __builtin_amdgcn_mfma_f32_16x16x32_bf16(
            af[mi], bfv[ni], accO[mi][ni], 0, 0, 0);
  }
#pragma unroll
  for (int mi = 0; mi < 2; ++mi)
#pragma unroll
    for (int r = 0; r < 4; ++r) {
      int i = wm + mi * 16 + rq + r;
#pragma unroll
      for (int ni = 0; ni < 2; ++ni) {
        int e = wn + ni * 16 + cloc;
        routb[base + (size_t)i * 512 + e] = f2bfu(accO[mi][ni][r]);
      }
    }
}

// ---------------------------------------------------------------------------
// K5: gemm2 (512 blocks, TN=64): out = (h*g) @ Wo + bo + r_out
// ---------------------------------------------------------------------------
__global__ __launch_bounds__(256) void k5_gemm2(
    const u16* __restrict__ hgbf, const u16* __restrict__ Wto,
    const float* __restrict__ bo, float* __restrict__ out,
    const u16* __restrict__ routb) {
  __shared__ __align__(16) u16 smem[TM * BK + 64 * BK];  // 24 KB
  gemm_tile64(blockIdx.x & 7, blockIdx.x >> 3, hgbf, Wto, bo, out, routb,
              smem, smem + TM * BK, threadIdx.x);
}

// ---------------------------------------------------------------------------
extern "C" void kernel_launch(void* const* d_in, const int* in_sizes, int n_in,
                              void* d_out, int out_size, void* d_ws, size_t ws_size,
                              hipStream_t stream) {
  const float* q  = (const float*)d_in[0];
  const float* k  = (const float*)d_in[1];
  const float* v  = (const float*)d_in[2];
  const float* Wa = (const float*)d_in[3];
  const float* ba = (const float*)d_in[4];
  const float* Wb = (const float*)d_in[5];
  const float* bb = (const float*)d_in[6];
  const float* Wg = (const float*)d_in[7];
  const float* bg = (const float*)d_in[8];
  const float* Wo = (const float*)d_in[9];
  const float* bo = (const float*)d_in[10];
  float* out = (float*)d_out;
  float* ws = (float*)d_ws;

  const size_t NEL = (size_t)BB * TT * DIM;  // 4,194,304
  float* SA = ws;
  float* SB = SA + NSC * 2048;
  u16* up = (u16*)(SB + NSC * 2048);
  u16* Ab16  = up;  up += NEL;               // a bf16
  u16* Bb16  = up;  up += NEL;               // b bf16
  u16* Gb16  = up;  up += NEL;               // g bf16
  u16* qbf   = up;  up += NEL;               // q bf16
  u16* hgbf  = up;  up += NEL;               // h*g bf16
  u16* WtAll = up;  up += 4 * DIM * DIM;     // W^T bf16
  u16* KVTb  = up;  up += (size_t)NC * BHN * 4096;
  u16* Ptb   = up;  up += (size_t)NC * BHN * 4096;
  u16* VTg   = up;  up += (size_t)BHN * 64 * TT;
  u16* routb = up;  up += NEL;               // r_out bf16

  k1_prep_retkv<<<6144, 256, 0, stream>>>(q, qbf, Wa, Wb, Wg, Wo, WtAll,
                                          k, v, KVTb, VTg);

  k2_gemm1_retscan<<<1280, 256, 0, stream>>>(qbf, WtAll, ba, bb, bg,
                                             Ab16, Bb16, Gb16, KVTb, Ptb);

  k3_part<<<512, 256, 0, stream>>>(Ab16, Bb16, SA, SB);

  k4_apply_retout<<<1536, 256, 0, stream>>>(Ab16, Bb16, Gb16, SA, SB, hgbf,
                                            qbf, k, VTg, Ptb, routb);

  k5_gemm2<<<512, 256, 0, stream>>>(hgbf, WtAll + 3 * DIM * DIM,
                                    bo, out, routb);
}